// Round 18
// baseline (28.849 us; speedup 1.0000x reference)
//
#include <hip/hip_runtime.h>
#include <math.h>

#define TWO_PI_F 6.28318530717958647692f

typedef unsigned int u32;
typedef __attribute__((ext_vector_type(4))) float    f4;
typedef __attribute__((ext_vector_type(16))) float   f16v;
typedef __attribute__((ext_vector_type(2))) float    f2;
typedef __attribute__((ext_vector_type(2))) _Float16 h2;
typedef __attribute__((ext_vector_type(4))) _Float16 h4;
typedef __attribute__((ext_vector_type(8))) _Float16 h8;

union B8 { h8 v; h4 q[2]; };
union C2 { u32 w[2]; h4 v; };
union P4 { h2 a[4]; h8 v; };

#if __has_builtin(__builtin_amdgcn_cvt_pkrtz)
__device__ __forceinline__ h2 CVTPK(float a, float b) {
    return __builtin_bit_cast(h2, __builtin_amdgcn_cvt_pkrtz(a, b));
}
#else
__device__ __forceinline__ h2 CVTPK(float a, float b) {
    return (h2){(_Float16)a, (_Float16)b};
}
#endif

// ---------------------------------------------------------------------------
// Setup kernel (ONE block, 64 threads): all block-invariant precompute,
// previously redone by each of the 2080 main blocks.
//   wpre[h][16] f16 : V^T row for h = [W1[0:8,h] | wc ws zc 0 0 0 0 0]
//   Lp[11]          : 0.25 * V w2 (for the separable linear relu-term)
//   w2perm[64]      : 0.25*w2 permuted to the C-fragment row layout
// ---------------------------------------------------------------------------
__global__ __launch_bounds__(64) void gd_setup(
    const float* __restrict__ z,  const float* __restrict__ W1,
    const float* __restrict__ b1, const float* __restrict__ W2,
    _Float16* __restrict__ wpre, float* __restrict__ Lp,
    float* __restrict__ w2perm)
{
    int t = threadIdx.x;   // == h

    float zc = b1[t];
#pragma unroll
    for (int zz = 0; zz < 32; ++zz)
        zc = fmaf(z[zz], W1[(10 + zz) * 64 + t], zc);

    h8 row0, row1;
#pragma unroll
    for (int k = 0; k < 8; ++k) row0[k] = (_Float16)W1[k * 64 + t];
    row1 = (h8)0;
    row1[0] = (_Float16)W1[8 * 64 + t];   // wc
    row1[1] = (_Float16)W1[9 * 64 + t];   // ws
    row1[2] = (_Float16)zc;               // bias via "1" feature
    *(h8*)&wpre[t * 16]     = row0;
    *(h8*)&wpre[t * 16 + 8] = row1;

    // Lp[k] = 0.25 * sum_h V[k,h]*w2[h] : 64-lane butterfly
    float q25 = 0.25f * W2[t];
    float lv[11];
#pragma unroll
    for (int k = 0; k < 8; ++k) lv[k] = (float)row0[k] * q25;
    lv[8]  = (float)row1[0] * q25;
    lv[9]  = (float)row1[1] * q25;
    lv[10] = zc * q25;
#pragma unroll
    for (int off = 32; off; off >>= 1)
#pragma unroll
        for (int k = 0; k < 11; ++k)
            lv[k] += __shfl_xor(lv[k], off);
    if (t == 0) {
#pragma unroll
        for (int k = 0; k < 11; ++k) Lp[k] = lv[k];
    }

    // w2perm[H*32 + q*16 + e] = 0.25 * w2[(e&3) + 8*(e>>2) + 4q + 32H]
    int e = t & 15, q_ = (t >> 4) & 1, H = t >> 5;
    w2perm[t] = 0.25f * W2[(e & 3) + 8 * (e >> 2) + 4 * q_ + 32 * H];
}

// ---------------------------------------------------------------------------
// Main kernel: r17 structure, per-block setup stripped to s-dependent work.
// A-frags / w2 / Lp load from global (L1/L2-resident broadcast) at entry so
// latency hides under trig+P2 setup. 2080 triangular blocks, 256 threads.
// ---------------------------------------------------------------------------
__global__ __launch_bounds__(256, 3) void gd_mfma(
    const float* __restrict__ s,   const _Float16* __restrict__ wpre,
    const float* __restrict__ Lpg, const float* __restrict__ w2perm,
    const float* __restrict__ b2v, float* __restrict__ out, int N, int NB)
{
    __shared__ __attribute__((aligned(16))) h4 peb[64];           // 512B
    __shared__ __attribute__((aligned(16))) h2 P2[1024];          // 4KB {ct,st}
    __shared__ __attribute__((aligned(16))) float S[2][32][36];   // 9.2KB
    __shared__ __attribute__((aligned(16))) f4 strig2[64];        // 1KB
    __shared__ float LA[64], LB[64];                              // 512B

    // --- triangular block decode: u -> (bi, bj), bj >= bi ---
    int u = blockIdx.x;
    int M = 2 * NB + 1;
    float disc = (float)(M * M - 8 * u);
    int bi = (int)(((float)M - sqrtf(disc)) * 0.5f);
    if (bi < 0) bi = 0;
    if (bi > NB - 1) bi = NB - 1;
    while (bi > 0 && bi * (M - bi) / 2 > u) --bi;
    while ((bi + 1) * (M - (bi + 1)) / 2 <= u) ++bi;
    int bj = bi + (u - bi * (M - bi) / 2);

    int t    = threadIdx.x;
    int lane = t & 63;
    int n    = lane & 31;
    int q    = lane >> 5;

    // --- issue block-invariant global loads FIRST (latency hides below) ---
    h8 afr[2];
    f4 w2v4[2][4];
#pragma unroll
    for (int H = 0; H < 2; ++H) {
        afr[H] = *(const h8*)&wpre[(H * 32 + n) * 16 + q * 8];
#pragma unroll
        for (int g = 0; g < 4; ++g)
            w2v4[H][g] = *(const f4*)&w2perm[H * 32 + q * 16 + g * 4];
    }
    float Lp8r = Lpg[8], Lp9r = Lpg[9];

    // --- s-dependent setup (t<64) ---
    if (t < 64) {
        int grow = (t < 32) ? (bi * 32 + t) : (bj * 32 + (t - 32));
        float ang = TWO_PI_F * s[grow];
        float c1 = __cosf(ang), s1 = __sinf(ang);
        float c2 = c1 * c1 - s1 * s1, s2 = 2.0f * c1 * s1;
        strig2[t] = (f4){c1, s1, c2, s2};
        peb[t]    = (h4){(_Float16)c1, (_Float16)s1, (_Float16)c2, (_Float16)s2};
        LA[t] = fmaf(Lpg[0], c1, fmaf(Lpg[1], s1,
                 fmaf(Lpg[2], c2, fmaf(Lpg[3], s2, Lpg[10]))));
        LB[t] = fmaf(Lpg[4], c1, fmaf(Lpg[5], s1,
                 fmaf(Lpg[6], c2, Lpg[7] * s2)));
    }
    __syncthreads();

    // --- P2 build: 4 cells/thread, one b128 store ---
    {
        int base = t * 4;
        int il = base >> 5, j0 = base & 31;
        f4 ci = strig2[il];
        P4 pk;
#pragma unroll
        for (int c = 0; c < 4; ++c) {
            f4 cj = strig2[32 + j0 + c];
            float ctv = fmaf(ci.x, cj.x, ci.y * cj.y);
            float stv = fabsf(fmaf(ci.y, cj.x, -(ci.x * cj.y)));
            pk.a[c] = CVTPK(ctv, stv);
        }
        *(h8*)&P2[base] = pk.v;
    }
    __syncthreads();

    // --- phase 2: dual-stream MFMA loop, abs-fma epilogue + separable lin ---
    int wv   = t >> 6;
    int o    = wv >> 1;          // orientation: wave-invariant
    int base = (wv & 1) * 16;    // il base

    h4 pe_inv = peb[32 + n];     // fixed-role pe row (iteration-invariant)
    float laneInv = o ? LA[32 + n] : LB[32 + n];

    const float* w2v0 = (const float*)&w2v4[0][0];
    const float* w2v1 = (const float*)&w2v4[1][0];

#pragma unroll
    for (int i = 0; i < 8; ++i) {
        int ilA = base + i;
        int ilB = base + i + 8;

        h4 varA = peb[ilA];                        // broadcast (uniform addr)
        h4 varB = peb[ilB];
        u32 pwA = *(const u32*)&P2[ilA * 32 + n];  // conflict-free b32
        u32 pwB = *(const u32*)&P2[ilB * 32 + n];
        float rowA = o ? LB[ilA] : LA[ilA];        // uniform broadcast reads
        float rowB = o ? LB[ilB] : LA[ilB];

        B8 bA, bB;
        {
            h4 pa = o ? pe_inv : varA;
            h4 pb = o ? varA : pe_inv;
            C2 cc; cc.w[0] = pwA; cc.w[1] = 0x00003C00u;   // {ct,st,1,0}
            bA.q[0] = q ? cc.v : pa;
            bA.q[1] = q ? (h4)0 : pb;
        }
        {
            h4 pa = o ? pe_inv : varB;
            h4 pb = o ? varB : pe_inv;
            C2 cc; cc.w[0] = pwB; cc.w[1] = 0x00003C00u;
            bB.q[0] = q ? cc.v : pa;
            bB.q[1] = q ? (h4)0 : pb;
        }

        f16v a0A = __builtin_amdgcn_mfma_f32_32x32x16_f16(afr[0], bA.v, (f16v)(0.0f), 0, 0, 0);
        f16v a1A = __builtin_amdgcn_mfma_f32_32x32x16_f16(afr[1], bA.v, (f16v)(0.0f), 0, 0, 0);
        f16v a0B = __builtin_amdgcn_mfma_f32_32x32x16_f16(afr[0], bB.v, (f16v)(0.0f), 0, 0, 0);
        f16v a1B = __builtin_amdgcn_mfma_f32_32x32x16_f16(afr[1], bB.v, (f16v)(0.0f), 0, 0, 0);

        float cA0 = 0.f, cA1 = 0.f, cA2 = 0.f, cA3 = 0.f;
        float cB0 = 0.f, cB1 = 0.f, cB2 = 0.f, cB3 = 0.f;
#pragma unroll
        for (int e = 0; e < 8; ++e) {      // |src| is a free VOP3 modifier
            cA0 = fmaf(fabsf(a0A[e]),     w2v0[e],     cA0);
            cA1 = fmaf(fabsf(a0A[e + 8]), w2v0[e + 8], cA1);
            cA2 = fmaf(fabsf(a1A[e]),     w2v1[e],     cA2);
            cA3 = fmaf(fabsf(a1A[e + 8]), w2v1[e + 8], cA3);
            cB0 = fmaf(fabsf(a0B[e]),     w2v0[e],     cB0);
            cB1 = fmaf(fabsf(a0B[e + 8]), w2v0[e + 8], cB1);
            cB2 = fmaf(fabsf(a1B[e]),     w2v1[e],     cB2);
            cB3 = fmaf(fabsf(a1B[e + 8]), w2v1[e + 8], cB3);
        }
        float psA = (cA0 + cA1) + (cA2 + cA3);
        float psB = (cB0 + cB1) + (cB2 + cB3);
        psA += __shfl_xor(psA, 32);        // abs part: combine the two K-halves
        psB += __shfl_xor(psB, 32);

        // linear part (exact matmul identity, separable)
        h2 ppA = __builtin_bit_cast(h2, pwA);
        h2 ppB = __builtin_bit_cast(h2, pwB);
        float linA = rowA + laneInv;
        linA = fmaf((float)ppA[0], Lp8r, linA);
        linA = fmaf((float)ppA[1], Lp9r, linA);
        float linB = rowB + laneInv;
        linB = fmaf((float)ppB[0], Lp8r, linB);
        linB = fmaf((float)ppB[1], Lp9r, linB);
        psA += linA;
        psB += linB;

        if (q == 0) {
            S[o][ilA][n] = psA;
            S[o][ilB][n] = psB;
        }
    }
    __syncthreads();

    // --- phase 3: symmetrized output + mirror (coalesced f4 stores) ---
    float b2 = b2v[0];
    {
        int il = t >> 3;
        int j0 = (t & 7) * 4;
        f4 a = *(const f4*)&S[0][il][j0];
        f4 b = *(const f4*)&S[1][il][j0];
        f4 v;
#pragma unroll
        for (int c = 0; c < 4; ++c) {
            float x = a[c] + b[c] + b2;
            if (bi == bj && il == j0 + c) x = -1e9f;
            v[c] = x;
        }
        *(f4*)&out[(size_t)(bi * 32 + il) * N + bj * 32 + j0] = v;

        if (bj > bi) {
            int jl = t >> 3;
            int i0 = (t & 7) * 4;
            f4 m;
#pragma unroll
            for (int c = 0; c < 4; ++c)
                m[c] = S[0][i0 + c][jl] + S[1][i0 + c][jl] + b2;
            *(f4*)&out[(size_t)(bj * 32 + jl) * N + bi * 32 + i0] = m;
        }
    }
}

extern "C" void kernel_launch(void* const* d_in, const int* in_sizes, int n_in,
                              void* d_out, int out_size, void* d_ws, size_t ws_size,
                              hipStream_t stream) {
    const float* z  = (const float*)d_in[0];  // [32]
    const float* s  = (const float*)d_in[1];  // [N]
    const float* W1 = (const float*)d_in[2];  // [42,64]
    const float* b1 = (const float*)d_in[3];  // [64]
    const float* W2 = (const float*)d_in[4];  // [64]
    const float* b2 = (const float*)d_in[5];  // [1]
    int N = in_sizes[1];                      // 2048

    _Float16* wpre   = (_Float16*)d_ws;                 // 64*16 f16 = 2KB
    float*    Lp     = (float*)(wpre + 64 * 16);        // 12 f32
    float*    w2perm = Lp + 12;                         // 64 f32

    float* out = (float*)d_out;
    int NB = N / 32;
    int nblk = NB * (NB + 1) / 2;             // 2080 for N=2048

    gd_setup<<<1, 64, 0, stream>>>(z, W1, b1, W2, wpre, Lp, w2perm);
    gd_mfma<<<nblk, 256, 0, stream>>>(s, wpre, Lp, w2perm, b2, out, N, NB);
}

// Round 19
// 27.021 us; speedup vs baseline: 1.0677x; 1.0677x over previous
//
#include <hip/hip_runtime.h>
#include <math.h>

#define TWO_PI_F 6.28318530717958647692f

typedef unsigned int u32;
typedef __attribute__((ext_vector_type(4))) float    f4;
typedef __attribute__((ext_vector_type(16))) float   f16v;
typedef __attribute__((ext_vector_type(2))) float    f2;
typedef __attribute__((ext_vector_type(2))) _Float16 h2;
typedef __attribute__((ext_vector_type(4))) _Float16 h4;
typedef __attribute__((ext_vector_type(8))) _Float16 h8;

union B8 { h8 v; h4 q[2]; };
union C2 { u32 w[2]; h4 v; };
union P4 { h2 a[4]; h8 v; };

#if __has_builtin(__builtin_amdgcn_cvt_pkrtz)
__device__ __forceinline__ h2 CVTPK(float a, float b) {
    return __builtin_bit_cast(h2, __builtin_amdgcn_cvt_pkrtz(a, b));
}
#else
__device__ __forceinline__ h2 CVTPK(float a, float b) {
    return (h2){(_Float16)a, (_Float16)b};
}
#endif

// ---------------------------------------------------------------------------
// r17 structure + orientation swap moved to the A side:
//   o=1 waves load A-frag with k-halves swapped ([W1[4:8]|W1[0:4]]) at SETUP
//   -> the per-iteration B-fragment is orientation-independent:
//      q[1] = (q ? 0 : pe_col)  is iteration-INVARIANT (hoisted),
//      q[0] = (q ? {P2,1,0} : pe_row[il])  is 2 cndmasks.
//   Loop body ~72 inst (was ~95): B-marshal cut ~4x.
// Epilogue: relu-split (abs as free VOP3 src modifier) + separable linear.
// 2080 upper-triangular 32x32 blocks, 256 threads, 4 MFMAs/iter dual-stream.
// ---------------------------------------------------------------------------
__global__ __launch_bounds__(256, 3) void gd_mfma(
    const float* __restrict__ z,  const float* __restrict__ s,
    const float* __restrict__ W1, const float* __restrict__ b1,
    const float* __restrict__ W2, const float* __restrict__ b2v,
    float* __restrict__ out, int N, int NB)
{
    __shared__ __attribute__((aligned(16))) _Float16 Ald[64][24]; // 3KB
    __shared__ __attribute__((aligned(16))) h4 peb[64];           // 512B
    __shared__ __attribute__((aligned(16))) h2 P2[1024];          // 4KB {ct,st}
    __shared__ __attribute__((aligned(16))) float S[2][32][36];   // 9.2KB
    __shared__ __attribute__((aligned(16))) f4 strig2[64];        // 1KB
    __shared__ __attribute__((aligned(16))) float w2f[64];        // 256B
    __shared__ float Lp[12];                                      // 48B
    __shared__ float LA[64], LB[64];                              // 512B

    // --- triangular block decode: u -> (bi, bj), bj >= bi ---
    int u = blockIdx.x;
    int M = 2 * NB + 1;
    float disc = (float)(M * M - 8 * u);
    int bi = (int)(((float)M - sqrtf(disc)) * 0.5f);
    if (bi < 0) bi = 0;
    if (bi > NB - 1) bi = NB - 1;
    while (bi > 0 && bi * (M - bi) / 2 > u) --bi;
    while ((bi + 1) * (M - (bi + 1)) / 2 <= u) ++bi;
    int bj = bi + (u - bi * (M - bi) / 2);

    int t    = threadIdx.x;
    int lane = t & 63;

    if (t < 64) {                        // wave 0: trig + pe + V^T rows + Lp
        int grow = (t < 32) ? (bi * 32 + t) : (bj * 32 + (t - 32));
        float ang = TWO_PI_F * s[grow];
        float c1 = __cosf(ang), s1 = __sinf(ang);
        float c2 = c1 * c1 - s1 * s1, s2 = 2.0f * c1 * s1;
        strig2[t] = (f4){c1, s1, c2, s2};
        peb[t]    = (h4){(_Float16)c1, (_Float16)s1, (_Float16)c2, (_Float16)s2};
        float w2t = W2[t];
        w2f[t] = w2t;

        float zc = b1[t];
#pragma unroll
        for (int zz = 0; zz < 32; ++zz)
            zc = fmaf(z[zz], W1[(10 + zz) * 64 + t], zc);

        h8 row0, row1;
#pragma unroll
        for (int k = 0; k < 8; ++k) row0[k] = (_Float16)W1[k * 64 + t];
        row1 = (h8)0;
        row1[0] = (_Float16)W1[8 * 64 + t];   // wc
        row1[1] = (_Float16)W1[9 * 64 + t];   // ws
        row1[2] = (_Float16)zc;               // bias via "1" feature
        *(h8*)&Ald[t][0] = row0;
        *(h8*)&Ald[t][8] = row1;

        // Lp[k] = 0.25 * sum_h V[k,h]*w2[h] : 64-lane butterfly (wave 0)
        float q25 = 0.25f * w2t;
        float lv[11];
#pragma unroll
        for (int k = 0; k < 8; ++k) lv[k] = (float)row0[k] * q25;
        lv[8]  = (float)row1[0] * q25;
        lv[9]  = (float)row1[1] * q25;
        lv[10] = zc * q25;
#pragma unroll
        for (int off = 32; off; off >>= 1)
#pragma unroll
            for (int k = 0; k < 11; ++k)
                lv[k] += __shfl_xor(lv[k], off);
        if (t == 0) {
#pragma unroll
            for (int k = 0; k < 11; ++k) Lp[k] = lv[k];
        }
    }
    __syncthreads();

    // --- P2 build (all threads) + LA/LB rows (t<64) ---
    {
        int base = t * 4;
        int il = base >> 5, j0 = base & 31;
        f4 ci = strig2[il];
        P4 pk;
#pragma unroll
        for (int c = 0; c < 4; ++c) {
            f4 cj = strig2[32 + j0 + c];
            float ctv = fmaf(ci.x, cj.x, ci.y * cj.y);
            float stv = fabsf(fmaf(ci.y, cj.x, -(ci.x * cj.y)));
            pk.a[c] = CVTPK(ctv, stv);
        }
        *(h8*)&P2[base] = pk.v;
    }
    if (t < 64) {
        f4 tg = strig2[t];
        LA[t] = fmaf(Lp[0], tg.x, fmaf(Lp[1], tg.y,
                 fmaf(Lp[2], tg.z, fmaf(Lp[3], tg.w, Lp[10]))));
        LB[t] = fmaf(Lp[4], tg.x, fmaf(Lp[5], tg.y,
                 fmaf(Lp[6], tg.z, Lp[7] * tg.w)));
    }

    int n  = lane & 31;
    int q  = lane >> 5;
    int wv = t >> 6;
    int o  = wv >> 1;            // orientation: wave-invariant

    // 0.25*w2 f32 registers matched to C row layout
    float w2v[2][16];
#pragma unroll
    for (int H = 0; H < 2; ++H)
#pragma unroll
        for (int e = 0; e < 16; ++e)
            w2v[H][e] = 0.25f * w2f[(e & 3) + 8 * (e >> 2) + 4 * q + 32 * H];
    __syncthreads();

    // A-frags: o=1 waves swap the k0..3 / k4..7 halves (orientation on A side)
    h8 afr[2];
#pragma unroll
    for (int H = 0; H < 2; ++H) {
        int hh = H * 32 + n;
        B8 af;
        if (q == 0) {
            af.q[0] = *(const h4*)&Ald[hh][o ? 4 : 0];
            af.q[1] = *(const h4*)&Ald[hh][o ? 0 : 4];
        } else {
            af.v = *(const h8*)&Ald[hh][8];
        }
        afr[H] = af.v;
    }

    // --- phase 2: dual-stream MFMA loop, o-free B-frags ---
    int base = (wv & 1) * 16;    // il base

    h4 pe_col = peb[32 + n];                 // lane's column pe (invariant)
    h4 bq1    = q ? (h4)0 : pe_col;          // B-frag half 2: FULLY invariant
    const float* Lrow = o ? LB : LA;         // hoisted wave-uniform selects
    float laneInv = o ? LA[32 + n] : LB[32 + n];
    float Lp8r = Lp[8], Lp9r = Lp[9];

#pragma unroll
    for (int i = 0; i < 8; ++i) {
        int ilA = base + i;
        int ilB = base + i + 8;

        h4 varA = peb[ilA];                        // broadcast (uniform addr)
        h4 varB = peb[ilB];
        u32 pwA = *(const u32*)&P2[ilA * 32 + n];  // conflict-free b32
        u32 pwB = *(const u32*)&P2[ilB * 32 + n];
        float rowA = Lrow[ilA];                    // uniform broadcast reads
        float rowB = Lrow[ilB];

        B8 bA, bB;
        C2 ccA; ccA.w[0] = pwA; ccA.w[1] = 0x00003C00u;   // {ct,st,1,0}
        C2 ccB; ccB.w[0] = pwB; ccB.w[1] = 0x00003C00u;
        bA.q[0] = q ? ccA.v : varA;
        bA.q[1] = bq1;
        bB.q[0] = q ? ccB.v : varB;
        bB.q[1] = bq1;

        f16v a0A = __builtin_amdgcn_mfma_f32_32x32x16_f16(afr[0], bA.v, (f16v)(0.0f), 0, 0, 0);
        f16v a1A = __builtin_amdgcn_mfma_f32_32x32x16_f16(afr[1], bA.v, (f16v)(0.0f), 0, 0, 0);
        f16v a0B = __builtin_amdgcn_mfma_f32_32x32x16_f16(afr[0], bB.v, (f16v)(0.0f), 0, 0, 0);
        f16v a1B = __builtin_amdgcn_mfma_f32_32x32x16_f16(afr[1], bB.v, (f16v)(0.0f), 0, 0, 0);

        float cA0 = 0.f, cA1 = 0.f, cA2 = 0.f, cA3 = 0.f;
        float cB0 = 0.f, cB1 = 0.f, cB2 = 0.f, cB3 = 0.f;
#pragma unroll
        for (int e = 0; e < 8; ++e) {      // |src| is a free VOP3 modifier
            cA0 = fmaf(fabsf(a0A[e]),     w2v[0][e],     cA0);
            cA1 = fmaf(fabsf(a0A[e + 8]), w2v[0][e + 8], cA1);
            cA2 = fmaf(fabsf(a1A[e]),     w2v[1][e],     cA2);
            cA3 = fmaf(fabsf(a1A[e + 8]), w2v[1][e + 8], cA3);
            cB0 = fmaf(fabsf(a0B[e]),     w2v[0][e],     cB0);
            cB1 = fmaf(fabsf(a0B[e + 8]), w2v[0][e + 8], cB1);
            cB2 = fmaf(fabsf(a1B[e]),     w2v[1][e],     cB2);
            cB3 = fmaf(fabsf(a1B[e + 8]), w2v[1][e + 8], cB3);
        }
        float psA = (cA0 + cA1) + (cA2 + cA3);
        float psB = (cB0 + cB1) + (cB2 + cB3);
        psA += __shfl_xor(psA, 32);        // abs part: combine the two K-halves
        psB += __shfl_xor(psB, 32);

        // linear part (exact matmul identity, separable)
        h2 ppA = __builtin_bit_cast(h2, pwA);
        h2 ppB = __builtin_bit_cast(h2, pwB);
        float linA = rowA + laneInv;
        linA = fmaf((float)ppA[0], Lp8r, linA);
        linA = fmaf((float)ppA[1], Lp9r, linA);
        float linB = rowB + laneInv;
        linB = fmaf((float)ppB[0], Lp8r, linB);
        linB = fmaf((float)ppB[1], Lp9r, linB);
        psA += linA;
        psB += linB;

        if (q == 0) {
            S[o][ilA][n] = psA;
            S[o][ilB][n] = psB;
        }
    }
    __syncthreads();

    // --- phase 3: symmetrized output + mirror (coalesced f4 stores) ---
    float b2 = b2v[0];
    {
        int il = t >> 3;
        int j0 = (t & 7) * 4;
        f4 a = *(const f4*)&S[0][il][j0];
        f4 b = *(const f4*)&S[1][il][j0];
        f4 v;
#pragma unroll
        for (int c = 0; c < 4; ++c) {
            float x = a[c] + b[c] + b2;
            if (bi == bj && il == j0 + c) x = -1e9f;
            v[c] = x;
        }
        *(f4*)&out[(size_t)(bi * 32 + il) * N + bj * 32 + j0] = v;

        if (bj > bi) {
            int jl = t >> 3;
            int i0 = (t & 7) * 4;
            f4 m;
#pragma unroll
            for (int c = 0; c < 4; ++c)
                m[c] = S[0][i0 + c][jl] + S[1][i0 + c][jl] + b2;
            *(f4*)&out[(size_t)(bj * 32 + jl) * N + bi * 32 + i0] = m;
        }
    }
}

extern "C" void kernel_launch(void* const* d_in, const int* in_sizes, int n_in,
                              void* d_out, int out_size, void* d_ws, size_t ws_size,
                              hipStream_t stream) {
    const float* z  = (const float*)d_in[0];  // [32]
    const float* s  = (const float*)d_in[1];  // [N]
    const float* W1 = (const float*)d_in[2];  // [42,64]
    const float* b1 = (const float*)d_in[3];  // [64]
    const float* W2 = (const float*)d_in[4];  // [64]
    const float* b2 = (const float*)d_in[5];  // [1]
    int N = in_sizes[1];                      // 2048

    float* out = (float*)d_out;
    int NB = N / 32;
    int nblk = NB * (NB + 1) / 2;             // 2080 for N=2048
    gd_mfma<<<nblk, 256, 0, stream>>>(z, s, W1, b1, W2, b2, out, N, NB);
}